// Round 4
// baseline (251.797 us; speedup 1.0000x reference)
//
#include <hip/hip_runtime.h>
#include <math.h>

#define NPTS  131072
#define NPB   1024         // point blocks: 256 thr = 4 waves x 32 pts
#define NPAIRB 256         // pair blocks: 4 pairs/block (1 per wave)
#define DLOG2PIF 58.8120661f
#define DLOG2PI  58.81206612467475
#define SHIFT 92.0f        // fixed log-shift: maha <= ~220 here, exp2 arg stays in range
#define NEGHALF_LOG2E -0.72134752044f
#define LOG2E 1.44269504089f

typedef __attribute__((ext_vector_type(8)))  short short8;   // 8 bf16 = 4 VGPRs
typedef __attribute__((ext_vector_type(16))) float f32x16;   // MFMA 32x32 acc

static __device__ __forceinline__ unsigned bfh(float f) {    // fp32 -> bf16 bits (RNE)
  unsigned u = __float_as_uint(f);
  return (u + 0x7FFFu + ((u >> 16) & 1u)) >> 16;
}
static __device__ __forceinline__ float bfhf(float f) {
  return __uint_as_float(bfh(f) << 16);
}

static __device__ __forceinline__ void lse_merge(double& m, double& s, double m2, double s2) {
  if (m2 > m) { s = s*exp(m-m2) + s2; m = m2; }
  else        { s = s + s2*exp(m2-m); }
}

// ===== setup: Sigma, register chol, LDS-staged column-parallel L^-1, pack ==========
// Afrag layout: [cluster][slot(3)][lane(64)] x 16B.
// slot 0/1: bf16 B rows, k-chunk 0/1 (lane l: m=l&31, k=chunk*16+(l>>5)*8+j).
// slot 2: -c fragment (hi,lo at k=0,1; zeros elsewhere).
__global__ __launch_bounds__(64) void setup_kernel(
    const float* __restrict__ means, const float* __restrict__ chols,
    const float* __restrict__ wts,
    float* __restrict__ SigmaF, uint4* __restrict__ Afrag,
    float* __restrict__ Kc, float* __restrict__ Sg)
{
  const int k = blockIdx.x, tid = threadIdx.x, r = tid & 31, h = tid >> 5;
  __shared__ float Cs[32*33];
  __shared__ float Lsh[32*33];
  __shared__ float Bsh[32*33];
  for (int i = tid; i < 1024; i += 64) Cs[(i>>5)*33 + (i&31)] = chols[k*1024 + i];
  __syncthreads();
  float a[32];
  {
    float cr[32];
    #pragma unroll
    for (int m = 0; m < 32; m++) cr[m] = Cs[r*33 + m];
    #pragma unroll
    for (int c = 0; c < 32; c++) {               // Sigma row r = C_r . C_c + I
      float acc = (r == c) ? 1.0f : 0.0f;
      #pragma unroll
      for (int m = 0; m < 32; m++) acc = fmaf(cr[m], Cs[c*33+m], acc);
      a[c] = acc;
    }
  }
  if (tid < 32) {
    #pragma unroll
    for (int q = 0; q < 8; q++)
      ((float4*)(SigmaF + k*1024 + r*32))[q] = make_float4(a[4*q],a[4*q+1],a[4*q+2],a[4*q+3]);
  }
  // in-register cholesky: lane r holds row r (both wave-halves duplicate)
  float ldsum = 0.0f;
  #pragma unroll
  for (int j = 0; j < 32; j++) {
    float dd = __shfl(a[j], j);
    float sq = sqrtf(dd);
    float inv = 1.0f / sq;
    ldsum += __logf(sq);
    float l = a[j] * inv;
    #pragma unroll
    for (int e = j+1; e < 32; e++) {
      float le = __shfl(l, e);
      a[e] = (r >= e) ? fmaf(-l, le, a[e]) : a[e];
    }
    a[j] = (r == j) ? sq : ((r > j) ? l : a[j]);
  }
  // L rows -> LDS (a[] dead afterwards; kills register pressure)
  if (tid < 32) {
    #pragma unroll
    for (int j = 0; j < 32; j++) Lsh[r*33 + j] = a[j];
  }
  __syncthreads();
  // column-parallel inversion: lane c computes column c of B = L^-1
  // reads of Lsh are wave-uniform (broadcast, conflict-free)
  {
    float bcol[32];
    #pragma unroll
    for (int d = 0; d < 32; d++) {
      float s = (d == r) ? 1.0f : 0.0f;
      #pragma unroll
      for (int j = 0; j < d; j++) s = fmaf(-Lsh[d*33 + j], bcol[j], s);
      bcol[d] = s / Lsh[d*33 + d];
    }
    if (tid < 32) {
      #pragma unroll
      for (int d = 0; d < 32; d++) Bsh[d*33 + r] = bcol[d];   // stride-1 across lanes
    }
  }
  __syncthreads();
  // pack fragments from Bsh rows
  const int m = r;
  float t0[8], t1[8];
  #pragma unroll
  for (int j = 0; j < 8; j++) {
    t0[j] = Bsh[m*33 + h*8 + j];
    t1[j] = Bsh[m*33 + 16 + h*8 + j];
  }
  uint4 s0, s1, s2;
  s0 = make_uint4(bfh(t0[0])|(bfh(t0[1])<<16), bfh(t0[2])|(bfh(t0[3])<<16),
                  bfh(t0[4])|(bfh(t0[5])<<16), bfh(t0[6])|(bfh(t0[7])<<16));
  s1 = make_uint4(bfh(t1[0])|(bfh(t1[1])<<16), bfh(t1[2])|(bfh(t1[3])<<16),
                  bfh(t1[4])|(bfh(t1[5])<<16), bfh(t1[6])|(bfh(t1[7])<<16));
  float cv = 0.0f;                               // c_m = B row m . mu
  #pragma unroll
  for (int j = 0; j < 32; j++) cv = fmaf(Bsh[m*33 + j], means[k*32 + j], cv);
  unsigned ch = bfh(cv) ^ 0x8000u;               // -c_hi
  unsigned cl = bfh(cv - bfhf(cv)) ^ 0x8000u;    // -c_lo
  s2 = make_uint4((h == 0) ? (ch | (cl<<16)) : 0u, 0u, 0u, 0u);
  Afrag[(k*3 + 0)*64 + tid] = s0;
  Afrag[(k*3 + 1)*64 + tid] = s1;
  Afrag[(k*3 + 2)*64 + tid] = s2;
  if (tid == 0) {
    float wk = wts[k];
    float ld2 = 2.0f*ldsum + DLOG2PIF;           // logdet + D*log(2pi)
    Kc[k] = LOG2E*(SHIFT - 0.5f*ld2) + log2f(fabsf(wk));
    Sg[k] = (wk < 0.0f) ? -1.0f : 1.0f;
  }
}

// ===== work: MFMA point blocks (<NPB, no barriers in k-loop) + pair blocks =========
__global__ __launch_bounds__(256) void work_kernel(
    const float* __restrict__ X, const float* __restrict__ means, const float* __restrict__ wts,
    const float* __restrict__ SigmaF, const uint4* __restrict__ Afrag,
    const float* __restrict__ Kc, const float* __restrict__ Sg,
    double* __restrict__ pairv, double* __restrict__ partials)
{
  const int tid = threadIdx.x;
  if (blockIdx.x < NPB) {
    __shared__ float K2sh[32], sksh[32];
    __shared__ double redm[4], reds[4];
    const int lane = tid & 63, wv = tid >> 6, h = lane >> 5;
    const int n = (blockIdx.x*4 + wv)*32 + (lane & 31);
    if (tid < 32) { K2sh[tid] = Kc[tid]; sksh[tid] = Sg[tid]; }
    // lane's 16 dims of x (h picks the half of each 16-chunk) -> bf16 fragments
    const float* xp = X + (size_t)n*32 + h*8;
    float4 fa = *(const float4*)(xp);
    float4 fb = *(const float4*)(xp + 4);
    float4 fc = *(const float4*)(xp + 16);
    float4 fd = *(const float4*)(xp + 20);
    float v0[8] = {fa.x,fa.y,fa.z,fa.w,fb.x,fb.y,fb.z,fb.w};
    float v1[8] = {fc.x,fc.y,fc.z,fc.w,fd.x,fd.y,fd.z,fd.w};
    short8 xhi0, xhi1, x2c;
    #pragma unroll
    for (int j = 0; j < 8; j++) {
      xhi0[j] = (short)bfh(v0[j]);
      xhi1[j] = (short)bfh(v1[j]);
      x2c[j] = 0;
    }
    if (h == 0) { x2c[0] = (short)0x3F80; x2c[1] = (short)0x3F80; }  // X2=[1,1,0..]
    __syncthreads();
    const short8* Af = (const short8*)Afrag;
    float sF = 0.0f;
    #pragma unroll 2
    for (int k = 0; k < 32; k++) {
      short8 a0 = Af[(k*3 + 0)*64 + lane];
      short8 a1 = Af[(k*3 + 1)*64 + lane];
      short8 a2 = Af[(k*3 + 2)*64 + lane];
      f32x16 acc = {};
      acc = __builtin_amdgcn_mfma_f32_32x32x16_bf16(a0, xhi0, acc, 0,0,0);
      acc = __builtin_amdgcn_mfma_f32_32x32x16_bf16(a1, xhi1, acc, 0,0,0);
      acc = __builtin_amdgcn_mfma_f32_32x32x16_bf16(a2, x2c,  acc, 0,0,0);
      float maha = 0.0f;
      #pragma unroll
      for (int q = 0; q < 16; q++) maha = fmaf(acc[q], acc[q], maha);
      maha += __shfl_xor(maha, 32);             // combine row halves
      float arg = fmaf(maha, NEGHALF_LOG2E, K2sh[k]);
      sF = fmaf(sksh[k], exp2f(arg), sF);
    }
    // v = log(s^2) = 2*ln|sF| - 2*SHIFT; upper-half lanes are duplicates
    double vm, vs = 1.0;
    if (sF != 0.0f) vm = 2.0*log(fabs((double)sF)) - 2.0*(double)SHIFT;
    else          { vm = -1e300; vs = 0.0; }
    if (lane >= 32) { vm = -1e300; vs = 0.0; }
    #pragma unroll
    for (int off = 32; off > 0; off >>= 1) {
      double m2 = __shfl_down(vm, off);
      double s2 = __shfl_down(vs, off);
      lse_merge(vm, vs, m2, s2);
    }
    if (lane == 0) { redm[wv] = vm; reds[wv] = vs; }
    __syncthreads();
    if (tid == 0) {
      for (int w = 1; w < 4; w++) lse_merge(vm, vs, redm[w], reds[w]);
      partials[2*blockIdx.x]   = vm;
      partials[2*blockIdx.x+1] = vs;
    }
  } else {
    // ---- pairs: 1 pair per wave, all-register fp32 chol + column-sweep solve ----
    const int pb = blockIdx.x - NPB;
    const int w = tid >> 6, lane = tid & 63, r = lane & 31;
    const int pid = pb*4 + w, pi = pid >> 5, pj = pid & 31;
    float a[32];
    const float4* PA = (const float4*)(SigmaF + pi*1024 + r*32);
    const float4* PB = (const float4*)(SigmaF + pj*1024 + r*32);
    #pragma unroll
    for (int q = 0; q < 8; q++) {
      float4 u = PA[q], v = PB[q];
      a[4*q]=u.x+v.x; a[4*q+1]=u.y+v.y; a[4*q+2]=u.z+v.z; a[4*q+3]=u.w+v.w;
    }
    #pragma unroll
    for (int j = 0; j < 32; j++) {
      float dd = __shfl(a[j], j);
      float sq = sqrtf(dd);
      float inv = 1.0f / sq;
      float l = a[j] * inv;
      #pragma unroll
      for (int e = j+1; e < 32; e++) {
        float le = __shfl(l, e);
        a[e] = (r >= e) ? fmaf(-l, le, a[e]) : a[e];
      }
      a[j] = (r == j) ? sq : ((r > j) ? l : a[j]);
    }
    float acc = means[pi*32 + r] - means[pj*32 + r];
    float maha = 0.0f, ldsum = 0.0f;
    #pragma unroll
    for (int d = 0; d < 32; d++) {
      float dd = __shfl(a[d], d);
      float yd = __shfl(acc, d) / dd;
      maha = fmaf(yd, yd, maha);
      ldsum += __logf(dd);
      acc = (r > d) ? fmaf(-a[d], yd, acc) : acc;
    }
    if (lane == 0) pairv[pid] = -0.5 * ((double)maha + 2.0*(double)ldsum + DLOG2PI);
  }
}

// ===== final: merge 1024 point partials + 1024 pair terms -> scalar ================
__global__ __launch_bounds__(512) void final_kernel(
    const float* __restrict__ wts, const double* __restrict__ pairv,
    const double* __restrict__ partials, float* __restrict__ out)
{
  __shared__ double rm[8], rs[8], rzm[8], rzs[8];
  const int tid = threadIdx.x;
  double tm = partials[2*tid], ts = partials[2*tid+1];
  lse_merge(tm, ts, partials[2*(tid+512)], partials[2*(tid+512)+1]);
  double zm = -1e300, zs = 0.0;
  for (int p = tid; p < 1024; p += 512) {
    int i = p >> 5, j = p & 31;
    lse_merge(zm, zs, pairv[p], (double)wts[i] * (double)wts[j]);
  }
  #pragma unroll
  for (int off = 32; off > 0; off >>= 1) {
    double a = __shfl_down(tm, off), b = __shfl_down(ts, off);
    lse_merge(tm, ts, a, b);
    double c = __shfl_down(zm, off), d = __shfl_down(zs, off);
    lse_merge(zm, zs, c, d);
  }
  if ((tid & 63) == 0) { int w = tid >> 6; rm[w]=tm; rs[w]=ts; rzm[w]=zm; rzs[w]=zs; }
  __syncthreads();
  if (tid == 0) {
    for (int w = 1; w < 8; w++) { lse_merge(tm, ts, rm[w], rs[w]); lse_merge(zm, zs, rzm[w], rzs[w]); }
    double logT = tm + log(ts);
    double logz = zm + log(zs);
    out[0] = (float)((logz - logT) / (double)NPTS);
  }
}

extern "C" void kernel_launch(void* const* d_in, const int* in_sizes, int n_in,
                              void* d_out, int out_size, void* d_ws, size_t ws_size,
                              hipStream_t stream) {
  const float* X     = (const float*)d_in[0];
  const float* means = (const float*)d_in[1];
  const float* chols = (const float*)d_in[2];
  const float* wts   = (const float*)d_in[3];
  float* out = (float*)d_out;
  char* ws = (char*)d_ws;
  float*  SigmaF   = (float*)ws;                 // 131072 B
  uint4*  Afrag    = (uint4*)(ws + 131072);      // 32*3*64*16 = 98304 -> 229376
  float*  Kc       = (float*)(ws + 229376);      // 128  -> 229504
  float*  Sg       = (float*)(ws + 229504);      // 128  -> 229632
  double* pairv    = (double*)(ws + 229632);     // 8192 -> 237824
  double* partials = (double*)(ws + 237824);     // 16384 -> 254208

  setup_kernel<<<32, 64, 0, stream>>>(means, chols, wts, SigmaF, Afrag, Kc, Sg);
  work_kernel<<<NPB + NPAIRB, 256, 0, stream>>>(X, means, wts, SigmaF, Afrag,
                                                Kc, Sg, pairv, partials);
  final_kernel<<<1, 512, 0, stream>>>(wts, pairv, partials, out);
}

// Round 5
// 144.869 us; speedup vs baseline: 1.7381x; 1.7381x over previous
//
#include <hip/hip_runtime.h>
#include <math.h>

#define NPTS  131072
#define NWB   256          // work blocks: 512 thr, 512 points each
#define DLOG2PIF 58.8120661f
#define DLOG2PI  58.81206612467475
#define SHIFT 92.0f        // fixed log-shift keeps exp2 args in fp32 range
#define NEGHALF_LOG2E -0.72134752044f
#define LOG2E 1.44269504089f

typedef __attribute__((ext_vector_type(8)))  short short8;   // 8 bf16 = 4 VGPRs
typedef __attribute__((ext_vector_type(16))) float f32x16;   // MFMA 32x32 acc

static __device__ __forceinline__ unsigned bfh(float f) {    // fp32 -> bf16 bits (RNE)
  unsigned u = __float_as_uint(f);
  return (u + 0x7FFFu + ((u >> 16) & 1u)) >> 16;
}
static __device__ __forceinline__ float bfhf(float f) {
  return __uint_as_float(bfh(f) << 16);
}

static __device__ __forceinline__ void lse_merge(double& m, double& s, double m2, double s2) {
  if (m2 > m) { s = s*exp(m-m2) + s2; m = m2; }
  else        { s = s + s2*exp(m2-m); }
}

// ===== setup: 8 blocks x 256 thr; wave w handles cluster blockIdx*4+w ==============
// Afrag layout: [cluster][slot(3)][lane(64)] x 16B.
// slot 0/1: bf16 B rows, k-chunk 0/1 (lane l: m=l&31, k=chunk*16+(l>>5)*8+j).
// slot 2: -c fragment (hi,lo at k=0,1; zeros elsewhere).
__global__ __launch_bounds__(256) void setup_kernel(
    const float* __restrict__ means, const float* __restrict__ chols,
    const float* __restrict__ wts,
    float* __restrict__ SigmaF, uint4* __restrict__ Afrag,
    float* __restrict__ Kc, float* __restrict__ Sg)
{
  const int tid = threadIdx.x, wv = tid >> 6, lane = tid & 63;
  const int r = lane & 31, h = lane >> 5;
  const int k = blockIdx.x*4 + wv;
  __shared__ float CsA[4][1056];
  __shared__ float LsA[4][1056];
  __shared__ float BsA[4][1056];
  float* cs  = CsA[wv];
  float* lsh = LsA[wv];
  float* bsh = BsA[wv];
  for (int i = lane; i < 1024; i += 64) cs[(i>>5)*33 + (i&31)] = chols[k*1024 + i];
  __syncthreads();
  float a[32];
  {
    float cr[32];
    #pragma unroll
    for (int m = 0; m < 32; m++) cr[m] = cs[r*33 + m];
    #pragma unroll
    for (int c = 0; c < 32; c++) {               // Sigma row r = C_r . C_c + I
      float acc = (r == c) ? 1.0f : 0.0f;
      #pragma unroll
      for (int m = 0; m < 32; m++) acc = fmaf(cr[m], cs[c*33+m], acc);
      a[c] = acc;
    }
  }
  if (lane < 32) {
    #pragma unroll
    for (int q = 0; q < 8; q++)
      ((float4*)(SigmaF + k*1024 + r*32))[q] = make_float4(a[4*q],a[4*q+1],a[4*q+2],a[4*q+3]);
  }
  // in-register cholesky: lane r holds row r (both wave-halves duplicate)
  float ldsum = 0.0f;
  #pragma unroll
  for (int j = 0; j < 32; j++) {
    float dd = __shfl(a[j], j);
    float sq = sqrtf(dd);
    float inv = 1.0f / sq;
    ldsum += __logf(sq);
    float l = a[j] * inv;
    #pragma unroll
    for (int e = j+1; e < 32; e++) {
      float le = __shfl(l, e);
      a[e] = (r >= e) ? fmaf(-l, le, a[e]) : a[e];
    }
    a[j] = (r == j) ? sq : ((r > j) ? l : a[j]);
  }
  // L rows -> LDS
  if (lane < 32) {
    #pragma unroll
    for (int j = 0; j < 32; j++) lsh[r*33 + j] = a[j];
  }
  __syncthreads();
  // column-parallel inversion: lane c computes column c of B = L^-1 (broadcast reads)
  {
    float bcol[32];
    #pragma unroll
    for (int d = 0; d < 32; d++) {
      float s = (d == r) ? 1.0f : 0.0f;
      #pragma unroll
      for (int j = 0; j < d; j++) s = fmaf(-lsh[d*33 + j], bcol[j], s);
      bcol[d] = s / lsh[d*33 + d];
    }
    if (lane < 32) {
      #pragma unroll
      for (int d = 0; d < 32; d++) bsh[d*33 + r] = bcol[d];  // stride-1 across lanes
    }
  }
  __syncthreads();
  // pack fragments from bsh rows
  const int m = r;
  float t0[8], t1[8];
  #pragma unroll
  for (int j = 0; j < 8; j++) {
    t0[j] = bsh[m*33 + h*8 + j];
    t1[j] = bsh[m*33 + 16 + h*8 + j];
  }
  uint4 s0, s1, s2;
  s0 = make_uint4(bfh(t0[0])|(bfh(t0[1])<<16), bfh(t0[2])|(bfh(t0[3])<<16),
                  bfh(t0[4])|(bfh(t0[5])<<16), bfh(t0[6])|(bfh(t0[7])<<16));
  s1 = make_uint4(bfh(t1[0])|(bfh(t1[1])<<16), bfh(t1[2])|(bfh(t1[3])<<16),
                  bfh(t1[4])|(bfh(t1[5])<<16), bfh(t1[6])|(bfh(t1[7])<<16));
  float cv = 0.0f;                               // c_m = B row m . mu
  #pragma unroll
  for (int j = 0; j < 32; j++) cv = fmaf(bsh[m*33 + j], means[k*32 + j], cv);
  unsigned ch = bfh(cv) ^ 0x8000u;               // -c_hi
  unsigned cl = bfh(cv - bfhf(cv)) ^ 0x8000u;    // -c_lo
  s2 = make_uint4((h == 0) ? (ch | (cl<<16)) : 0u, 0u, 0u, 0u);
  Afrag[(k*3 + 0)*64 + lane] = s0;
  Afrag[(k*3 + 1)*64 + lane] = s1;
  Afrag[(k*3 + 2)*64 + lane] = s2;
  if (lane == 0) {
    float wk = wts[k];
    float ld2 = 2.0f*ldsum + DLOG2PIF;
    Kc[k] = LOG2E*(SHIFT - 0.5f*ld2) + log2f(fabsf(wk));
    Sg[k] = (wk < 0.0f) ? -1.0f : 1.0f;
  }
}

// ===== work: 256 blocks x 512 thr; LDS-staged fragments, 2 point-sets/wave =========
__global__ __launch_bounds__(512) void work_kernel(
    const float* __restrict__ X, const float* __restrict__ means,
    const float* __restrict__ SigmaF, const uint4* __restrict__ Afrag,
    const float* __restrict__ Kc, const float* __restrict__ Sg,
    double* __restrict__ pairv, double* __restrict__ partials)
{
  __shared__ uint4 fsh[16*3*64];                 // 48 KB: 16 clusters/phase
  __shared__ float K2sh[32], sksh[32];
  __shared__ double redm[8], reds[8];
  const int tid = threadIdx.x, wv = tid >> 6, lane = tid & 63, h = lane >> 5;
  if (tid < 32) { K2sh[tid] = Kc[tid]; sksh[tid] = Sg[tid]; }
  // two point-sets per wave: n0 (pass 0) and n0+256 (pass 1)
  const int n0 = blockIdx.x*512 + wv*32 + (lane & 31);
  short8 xh00, xh01, xh10, xh11, x2c;
  {
    const float* xp0 = X + (size_t)n0*32 + h*8;
    const float* xp1 = X + (size_t)(n0+256)*32 + h*8;
    float4 fa = *(const float4*)(xp0);
    float4 fb = *(const float4*)(xp0 + 4);
    float4 fc = *(const float4*)(xp0 + 16);
    float4 fd = *(const float4*)(xp0 + 20);
    float4 ga = *(const float4*)(xp1);
    float4 gb = *(const float4*)(xp1 + 4);
    float4 gc = *(const float4*)(xp1 + 16);
    float4 gd = *(const float4*)(xp1 + 20);
    float v00[8] = {fa.x,fa.y,fa.z,fa.w,fb.x,fb.y,fb.z,fb.w};
    float v01[8] = {fc.x,fc.y,fc.z,fc.w,fd.x,fd.y,fd.z,fd.w};
    float v10[8] = {ga.x,ga.y,ga.z,ga.w,gb.x,gb.y,gb.z,gb.w};
    float v11[8] = {gc.x,gc.y,gc.z,gc.w,gd.x,gd.y,gd.z,gd.w};
    #pragma unroll
    for (int j = 0; j < 8; j++) {
      xh00[j] = (short)bfh(v00[j]);  xh01[j] = (short)bfh(v01[j]);
      xh10[j] = (short)bfh(v10[j]);  xh11[j] = (short)bfh(v11[j]);
      x2c[j] = 0;
    }
    if (h == 0) { x2c[0] = (short)0x3F80; x2c[1] = (short)0x3F80; }  // X2=[1,1,0..]
  }
  float sF0 = 0.0f, sF1 = 0.0f;
  #pragma unroll 1
  for (int ph = 0; ph < 2; ph++) {
    __syncthreads();
    const uint4* src = Afrag + ph*3072;
    #pragma unroll
    for (int t = tid; t < 3072; t += 512) fsh[t] = src[t];
    __syncthreads();
    #pragma unroll 2
    for (int kk = 0; kk < 16; kk++) {
      const short8* fp = (const short8*)(fsh + kk*192);
      short8 a0 = fp[lane], a1 = fp[64+lane], a2 = fp[128+lane];
      const int kidx = ph*16 + kk;
      const float Kk = K2sh[kidx], sk = sksh[kidx];
      f32x16 acc0 = {}, acc1 = {};
      acc0 = __builtin_amdgcn_mfma_f32_32x32x16_bf16(a0, xh00, acc0, 0,0,0);
      acc0 = __builtin_amdgcn_mfma_f32_32x32x16_bf16(a1, xh01, acc0, 0,0,0);
      acc0 = __builtin_amdgcn_mfma_f32_32x32x16_bf16(a2, x2c,  acc0, 0,0,0);
      acc1 = __builtin_amdgcn_mfma_f32_32x32x16_bf16(a0, xh10, acc1, 0,0,0);
      acc1 = __builtin_amdgcn_mfma_f32_32x32x16_bf16(a1, xh11, acc1, 0,0,0);
      acc1 = __builtin_amdgcn_mfma_f32_32x32x16_bf16(a2, x2c,  acc1, 0,0,0);
      float m0 = 0.0f, m1 = 0.0f;
      #pragma unroll
      for (int q = 0; q < 16; q++) { m0 = fmaf(acc0[q], acc0[q], m0); m1 = fmaf(acc1[q], acc1[q], m1); }
      m0 += __shfl_xor(m0, 32);
      m1 += __shfl_xor(m1, 32);
      sF0 = fmaf(sk, exp2f(fmaf(m0, NEGHALF_LOG2E, Kk)), sF0);
      sF1 = fmaf(sk, exp2f(fmaf(m1, NEGHALF_LOG2E, Kk)), sF1);
    }
  }
  // per-lane merge of the two point-sets, then block reduction
  double vm = -1e300, vs = 0.0;
  if (sF0 != 0.0f) lse_merge(vm, vs, 2.0*log(fabs((double)sF0)) - 2.0*(double)SHIFT, 1.0);
  if (sF1 != 0.0f) lse_merge(vm, vs, 2.0*log(fabs((double)sF1)) - 2.0*(double)SHIFT, 1.0);
  if (lane >= 32) { vm = -1e300; vs = 0.0; }     // upper halves are duplicates
  #pragma unroll
  for (int off = 32; off > 0; off >>= 1) {
    double m2 = __shfl_down(vm, off);
    double s2 = __shfl_down(vs, off);
    lse_merge(vm, vs, m2, s2);
  }
  if (lane == 0) { redm[wv] = vm; reds[wv] = vs; }
  __syncthreads();
  if (tid == 0) {
    for (int w = 1; w < 8; w++) lse_merge(vm, vs, redm[w], reds[w]);
    partials[2*blockIdx.x]   = vm;
    partials[2*blockIdx.x+1] = vs;
  }
  // ---- pair tail: waves 0..3 each handle one (i,j) pair ----
  if (wv < 4) {
    const int pid = blockIdx.x*4 + wv, pi = pid >> 5, pj = pid & 31;
    const int r = lane & 31;
    float a[32];
    const float4* PA = (const float4*)(SigmaF + pi*1024 + r*32);
    const float4* PB = (const float4*)(SigmaF + pj*1024 + r*32);
    #pragma unroll
    for (int q = 0; q < 8; q++) {
      float4 u = PA[q], v = PB[q];
      a[4*q]=u.x+v.x; a[4*q+1]=u.y+v.y; a[4*q+2]=u.z+v.z; a[4*q+3]=u.w+v.w;
    }
    #pragma unroll
    for (int j = 0; j < 32; j++) {
      float dd = __shfl(a[j], j);
      float sq = sqrtf(dd);
      float inv = 1.0f / sq;
      float l = a[j] * inv;
      #pragma unroll
      for (int e = j+1; e < 32; e++) {
        float le = __shfl(l, e);
        a[e] = (r >= e) ? fmaf(-l, le, a[e]) : a[e];
      }
      a[j] = (r == j) ? sq : ((r > j) ? l : a[j]);
    }
    float acc = means[pi*32 + r] - means[pj*32 + r];
    float maha = 0.0f, ldsum = 0.0f;
    #pragma unroll
    for (int d = 0; d < 32; d++) {
      float dd = __shfl(a[d], d);
      float yd = __shfl(acc, d) / dd;
      maha = fmaf(yd, yd, maha);
      ldsum += __logf(dd);
      acc = (r > d) ? fmaf(-a[d], yd, acc) : acc;
    }
    if (lane == 0) pairv[pid] = -0.5 * ((double)maha + 2.0*(double)ldsum + DLOG2PI);
  }
}

// ===== final: merge 256 point partials + 1024 pair terms -> scalar =================
__global__ __launch_bounds__(512) void final_kernel(
    const float* __restrict__ wts, const double* __restrict__ pairv,
    const double* __restrict__ partials, float* __restrict__ out)
{
  __shared__ double rm[8], rs[8], rzm[8], rzs[8];
  const int tid = threadIdx.x;
  double tm = -1e300, ts = 0.0;
  if (tid < NWB) { tm = partials[2*tid]; ts = partials[2*tid+1]; }
  double zm = -1e300, zs = 0.0;
  for (int p = tid; p < 1024; p += 512) {
    int i = p >> 5, j = p & 31;
    lse_merge(zm, zs, pairv[p], (double)wts[i] * (double)wts[j]);
  }
  #pragma unroll
  for (int off = 32; off > 0; off >>= 1) {
    double a = __shfl_down(tm, off), b = __shfl_down(ts, off);
    lse_merge(tm, ts, a, b);
    double c = __shfl_down(zm, off), d = __shfl_down(zs, off);
    lse_merge(zm, zs, c, d);
  }
  if ((tid & 63) == 0) { int w = tid >> 6; rm[w]=tm; rs[w]=ts; rzm[w]=zm; rzs[w]=zs; }
  __syncthreads();
  if (tid == 0) {
    for (int w = 1; w < 8; w++) { lse_merge(tm, ts, rm[w], rs[w]); lse_merge(zm, zs, rzm[w], rzs[w]); }
    double logT = tm + log(ts);
    double logz = zm + log(zs);
    out[0] = (float)((logz - logT) / (double)NPTS);
  }
}

extern "C" void kernel_launch(void* const* d_in, const int* in_sizes, int n_in,
                              void* d_out, int out_size, void* d_ws, size_t ws_size,
                              hipStream_t stream) {
  const float* X     = (const float*)d_in[0];
  const float* means = (const float*)d_in[1];
  const float* chols = (const float*)d_in[2];
  const float* wts   = (const float*)d_in[3];
  float* out = (float*)d_out;
  char* ws = (char*)d_ws;
  float*  SigmaF   = (float*)ws;                 // 131072 B
  uint4*  Afrag    = (uint4*)(ws + 131072);      // 98304  -> 229376
  float*  Kc       = (float*)(ws + 229376);      // 128    -> 229504
  float*  Sg       = (float*)(ws + 229504);      // 128    -> 229632
  double* pairv    = (double*)(ws + 229632);     // 8192   -> 237824
  double* partials = (double*)(ws + 237824);     // 4096   -> 241920

  setup_kernel<<<8, 256, 0, stream>>>(means, chols, wts, SigmaF, Afrag, Kc, Sg);
  work_kernel<<<NWB, 512, 0, stream>>>(X, means, SigmaF, Afrag, Kc, Sg, pairv, partials);
  final_kernel<<<1, 512, 0, stream>>>(wts, pairv, partials, out);
}

// Round 6
// 143.024 us; speedup vs baseline: 1.7605x; 1.0129x over previous
//
#include <hip/hip_runtime.h>
#include <math.h>

#define NPTS  131072
#define NWB   256          // work blocks: 512 thr, 512 points each
#define DLOG2PIF 58.8120661f
#define DLOG2PI  58.81206612467475
#define SHIFT 92.0f        // fixed log-shift keeps exp2 args in fp32 range
#define NEGHALF_LOG2E -0.72134752044f
#define LOG2E 1.44269504089f

typedef __attribute__((ext_vector_type(8)))  short short8;   // 8 bf16 = 4 VGPRs
typedef __attribute__((ext_vector_type(16))) float f32x16;   // MFMA 32x32 acc

static __device__ __forceinline__ unsigned bfh(float f) {    // fp32 -> bf16 bits (RNE)
  unsigned u = __float_as_uint(f);
  return (u + 0x7FFFu + ((u >> 16) & 1u)) >> 16;
}
static __device__ __forceinline__ float bfhf(float f) {
  return __uint_as_float(bfh(f) << 16);
}

static __device__ __forceinline__ void lse_merge(double& m, double& s, double m2, double s2) {
  if (m2 > m) { s = s*exp(m-m2) + s2; m = m2; }
  else        { s = s + s2*exp(m2-m); }
}

// ===== setup: 8 blocks x 256 thr; wave wv handles cluster blockIdx*4+wv ============
// Sigma via 6 split-bf16 MFMAs; register chol; rolled LDS inversion; frag pack.
// Afrag layout: [cluster][slot(3)][lane(64)] x 16B (same as validated r5).
__global__ __launch_bounds__(256) void setup_kernel(
    const float* __restrict__ means, const float* __restrict__ chols,
    const float* __restrict__ wts,
    float* __restrict__ SigmaF, uint4* __restrict__ Afrag,
    float* __restrict__ Kc, float* __restrict__ Sg, unsigned* __restrict__ ticket)
{
  const int tid = threadIdx.x, wv = tid >> 6, lane = tid & 63;
  const int r = lane & 31, h = lane >> 5;
  const int k = blockIdx.x*4 + wv;
  __shared__ float SshA[4][1056];   // 32 x pitch-33 working matrix per wave
  __shared__ float blsA[4][1056];   // B = L^-1, [row][col], pitch 33
  float* Ssh = SshA[wv];
  float* bls = blsA[wv];
  if (blockIdx.x == 0 && tid == 0) *ticket = 0u;   // for work kernel's last-block gate

  // ---- load this lane's 16 dims of C row r (chunks 0/1), split bf16 hi/lo ----
  const float* cp = chols + (size_t)k*1024 + r*32 + h*8;
  float4 fa = *(const float4*)(cp);
  float4 fb = *(const float4*)(cp + 4);
  float4 fc = *(const float4*)(cp + 16);
  float4 fd = *(const float4*)(cp + 20);
  float v0[8] = {fa.x,fa.y,fa.z,fa.w,fb.x,fb.y,fb.z,fb.w};
  float v1[8] = {fc.x,fc.y,fc.z,fc.w,fd.x,fd.y,fd.z,fd.w};
  short8 hi0, hi1, lo0, lo1;
  #pragma unroll
  for (int j = 0; j < 8; j++) {
    hi0[j] = (short)bfh(v0[j]);  lo0[j] = (short)bfh(v0[j] - bfhf(v0[j]));
    hi1[j] = (short)bfh(v1[j]);  lo1[j] = (short)bfh(v1[j] - bfhf(v1[j]));
  }
  // ---- Sigma = C.C^T + I via MFMA (A and B fragments hold identical lane data) ----
  f32x16 acc = {};
  acc = __builtin_amdgcn_mfma_f32_32x32x16_bf16(hi0, hi0, acc, 0,0,0);
  acc = __builtin_amdgcn_mfma_f32_32x32x16_bf16(hi1, hi1, acc, 0,0,0);
  acc = __builtin_amdgcn_mfma_f32_32x32x16_bf16(hi0, lo0, acc, 0,0,0);
  acc = __builtin_amdgcn_mfma_f32_32x32x16_bf16(hi1, lo1, acc, 0,0,0);
  acc = __builtin_amdgcn_mfma_f32_32x32x16_bf16(lo0, hi0, acc, 0,0,0);
  acc = __builtin_amdgcn_mfma_f32_32x32x16_bf16(lo1, hi1, acc, 0,0,0);
  // C-layout: col = lane&31, row = (q&3) + 8*(q>>2) + 4*(lane>>5)
  #pragma unroll
  for (int q = 0; q < 16; q++) {
    int row = (q & 3) + 8*(q >> 2) + 4*h;
    float val = acc[q] + ((row == r) ? 1.0f : 0.0f);
    Ssh[row*33 + r] = val;
  }
  // Sigma -> global (for pair blocks)
  #pragma unroll 1
  for (int i = lane; i < 1024; i += 64) SigmaF[(size_t)k*1024 + i] = Ssh[(i>>5)*33 + (i&31)];
  // ---- register cholesky: lane r holds row r (both halves duplicate) ----
  float a[32];
  #pragma unroll
  for (int j = 0; j < 32; j++) a[j] = Ssh[r*33 + j];
  float ldsum = 0.0f;
  #pragma unroll
  for (int j = 0; j < 32; j++) {
    float dd = __shfl(a[j], j);
    float sq = sqrtf(dd);
    float inv = 1.0f / sq;
    ldsum += __logf(sq);
    float l = a[j] * inv;
    #pragma unroll
    for (int e = j+1; e < 32; e++) {
      float le = __shfl(l, e);
      a[e] = (r >= e) ? fmaf(-l, le, a[e]) : a[e];
    }
    a[j] = (r == j) ? sq : ((r > j) ? l : a[j]);
  }
  // L rows -> Ssh (overwrite Sigma; upper-tri junk never read)
  #pragma unroll
  for (int j = 0; j < 32; j++) Ssh[r*33 + j] = a[j];
  // ---- rolled column-parallel inversion: lane r computes column r of B ----
  #pragma unroll 1
  for (int d = 0; d < 32; d++) {
    float s = (d == r) ? 1.0f : 0.0f;
    for (int j = 0; j < d; j++) s = fmaf(-Ssh[d*33 + j], bls[j*33 + r], s);
    bls[d*33 + r] = s / Ssh[d*33 + d];
  }
  // ---- pack fragments: lane needs B[r][chunk*16 + h*8 + j] ----
  float t0[8], t1[8];
  #pragma unroll
  for (int j = 0; j < 8; j++) {
    t0[j] = bls[r*33 + h*8 + j];
    t1[j] = bls[r*33 + 16 + h*8 + j];
  }
  uint4 s0, s1, s2;
  s0 = make_uint4(bfh(t0[0])|(bfh(t0[1])<<16), bfh(t0[2])|(bfh(t0[3])<<16),
                  bfh(t0[4])|(bfh(t0[5])<<16), bfh(t0[6])|(bfh(t0[7])<<16));
  s1 = make_uint4(bfh(t1[0])|(bfh(t1[1])<<16), bfh(t1[2])|(bfh(t1[3])<<16),
                  bfh(t1[4])|(bfh(t1[5])<<16), bfh(t1[6])|(bfh(t1[7])<<16));
  float cvp = 0.0f;                              // c_r = B row r . mu (split over halves)
  #pragma unroll
  for (int j = 0; j < 8; j++) {
    cvp = fmaf(t0[j], means[k*32 + h*8 + j], cvp);
    cvp = fmaf(t1[j], means[k*32 + 16 + h*8 + j], cvp);
  }
  float cv = cvp + __shfl_xor(cvp, 32);
  unsigned ch = bfh(cv) ^ 0x8000u;               // -c_hi
  unsigned cl = bfh(cv - bfhf(cv)) ^ 0x8000u;    // -c_lo
  s2 = make_uint4((h == 0) ? (ch | (cl<<16)) : 0u, 0u, 0u, 0u);
  Afrag[(k*3 + 0)*64 + lane] = s0;
  Afrag[(k*3 + 1)*64 + lane] = s1;
  Afrag[(k*3 + 2)*64 + lane] = s2;
  if (lane == 0) {
    float wk = wts[k];
    float ld2 = 2.0f*ldsum + DLOG2PIF;
    Kc[k] = LOG2E*(SHIFT - 0.5f*ld2) + log2f(fabsf(wk));
    Sg[k] = (wk < 0.0f) ? -1.0f : 1.0f;
  }
}

// ===== work: 256 blocks x 512 thr; MFMA points + pair tail + fused last-block final
__global__ __launch_bounds__(512) void work_kernel(
    const float* __restrict__ X, const float* __restrict__ means,
    const float* __restrict__ wts,
    const float* __restrict__ SigmaF, const uint4* __restrict__ Afrag,
    const float* __restrict__ Kc, const float* __restrict__ Sg,
    double* __restrict__ pairv, double* __restrict__ partials,
    unsigned* __restrict__ ticket, float* __restrict__ out)
{
  __shared__ uint4 fsh[16*3*64];                 // 48 KB: 16 clusters/phase
  __shared__ float K2sh[32], sksh[32];
  __shared__ double redm[8], reds[8];
  __shared__ unsigned lastFlag;
  const int tid = threadIdx.x, wv = tid >> 6, lane = tid & 63, h = lane >> 5;
  if (tid < 32) { K2sh[tid] = Kc[tid]; sksh[tid] = Sg[tid]; }
  // two point-sets per wave: n0 and n0+256
  const int n0 = blockIdx.x*512 + wv*32 + (lane & 31);
  short8 xh00, xh01, xh10, xh11, x2c;
  {
    const float* xp0 = X + (size_t)n0*32 + h*8;
    const float* xp1 = X + (size_t)(n0+256)*32 + h*8;
    float4 fa = *(const float4*)(xp0);
    float4 fb = *(const float4*)(xp0 + 4);
    float4 fc = *(const float4*)(xp0 + 16);
    float4 fd = *(const float4*)(xp0 + 20);
    float4 ga = *(const float4*)(xp1);
    float4 gb = *(const float4*)(xp1 + 4);
    float4 gc = *(const float4*)(xp1 + 16);
    float4 gd = *(const float4*)(xp1 + 20);
    float v00[8] = {fa.x,fa.y,fa.z,fa.w,fb.x,fb.y,fb.z,fb.w};
    float v01[8] = {fc.x,fc.y,fc.z,fc.w,fd.x,fd.y,fd.z,fd.w};
    float v10[8] = {ga.x,ga.y,ga.z,ga.w,gb.x,gb.y,gb.z,gb.w};
    float v11[8] = {gc.x,gc.y,gc.z,gc.w,gd.x,gd.y,gd.z,gd.w};
    #pragma unroll
    for (int j = 0; j < 8; j++) {
      xh00[j] = (short)bfh(v00[j]);  xh01[j] = (short)bfh(v01[j]);
      xh10[j] = (short)bfh(v10[j]);  xh11[j] = (short)bfh(v11[j]);
      x2c[j] = 0;
    }
    if (h == 0) { x2c[0] = (short)0x3F80; x2c[1] = (short)0x3F80; }  // X2=[1,1,0..]
  }
  float sF0 = 0.0f, sF1 = 0.0f;
  #pragma unroll 1
  for (int ph = 0; ph < 2; ph++) {
    __syncthreads();
    const uint4* src = Afrag + ph*3072;
    #pragma unroll
    for (int t = tid; t < 3072; t += 512) fsh[t] = src[t];
    __syncthreads();
    #pragma unroll 2
    for (int kk = 0; kk < 16; kk++) {
      const short8* fp = (const short8*)(fsh + kk*192);
      short8 a0 = fp[lane], a1 = fp[64+lane], a2 = fp[128+lane];
      const int kidx = ph*16 + kk;
      const float Kk = K2sh[kidx], sk = sksh[kidx];
      f32x16 acc0 = {}, acc1 = {};
      acc0 = __builtin_amdgcn_mfma_f32_32x32x16_bf16(a0, xh00, acc0, 0,0,0);
      acc0 = __builtin_amdgcn_mfma_f32_32x32x16_bf16(a1, xh01, acc0, 0,0,0);
      acc0 = __builtin_amdgcn_mfma_f32_32x32x16_bf16(a2, x2c,  acc0, 0,0,0);
      acc1 = __builtin_amdgcn_mfma_f32_32x32x16_bf16(a0, xh10, acc1, 0,0,0);
      acc1 = __builtin_amdgcn_mfma_f32_32x32x16_bf16(a1, xh11, acc1, 0,0,0);
      acc1 = __builtin_amdgcn_mfma_f32_32x32x16_bf16(a2, x2c,  acc1, 0,0,0);
      float m0 = 0.0f, m1 = 0.0f;
      #pragma unroll
      for (int q = 0; q < 16; q++) { m0 = fmaf(acc0[q], acc0[q], m0); m1 = fmaf(acc1[q], acc1[q], m1); }
      m0 += __shfl_xor(m0, 32);
      m1 += __shfl_xor(m1, 32);
      sF0 = fmaf(sk, exp2f(fmaf(m0, NEGHALF_LOG2E, Kk)), sF0);
      sF1 = fmaf(sk, exp2f(fmaf(m1, NEGHALF_LOG2E, Kk)), sF1);
    }
  }
  // per-lane merge of the two point-sets, then block reduction
  double vm = -1e300, vs = 0.0;
  if (sF0 != 0.0f) lse_merge(vm, vs, 2.0*log(fabs((double)sF0)) - 2.0*(double)SHIFT, 1.0);
  if (sF1 != 0.0f) lse_merge(vm, vs, 2.0*log(fabs((double)sF1)) - 2.0*(double)SHIFT, 1.0);
  if (lane >= 32) { vm = -1e300; vs = 0.0; }     // upper halves are duplicates
  #pragma unroll
  for (int off = 32; off > 0; off >>= 1) {
    double m2 = __shfl_down(vm, off);
    double s2 = __shfl_down(vs, off);
    lse_merge(vm, vs, m2, s2);
  }
  if (lane == 0) { redm[wv] = vm; reds[wv] = vs; }
  __syncthreads();
  if (tid == 0) {
    for (int w = 1; w < 8; w++) lse_merge(vm, vs, redm[w], reds[w]);
    partials[2*blockIdx.x]   = vm;
    partials[2*blockIdx.x+1] = vs;
  }
  // ---- pair tail: waves 0..3 each handle one (i,j) pair ----
  if (wv < 4) {
    const int pid = blockIdx.x*4 + wv, pi = pid >> 5, pj = pid & 31;
    const int rr = lane & 31;
    float a[32];
    const float4* PA = (const float4*)(SigmaF + pi*1024 + rr*32);
    const float4* PB = (const float4*)(SigmaF + pj*1024 + rr*32);
    #pragma unroll
    for (int q = 0; q < 8; q++) {
      float4 u = PA[q], v = PB[q];
      a[4*q]=u.x+v.x; a[4*q+1]=u.y+v.y; a[4*q+2]=u.z+v.z; a[4*q+3]=u.w+v.w;
    }
    #pragma unroll
    for (int j = 0; j < 32; j++) {
      float dd = __shfl(a[j], j);
      float sq = sqrtf(dd);
      float inv = 1.0f / sq;
      float l = a[j] * inv;
      #pragma unroll
      for (int e = j+1; e < 32; e++) {
        float le = __shfl(l, e);
        a[e] = (rr >= e) ? fmaf(-l, le, a[e]) : a[e];
      }
      a[j] = (rr == j) ? sq : ((rr > j) ? l : a[j]);
    }
    float acc = means[pi*32 + rr] - means[pj*32 + rr];
    float maha = 0.0f, ldsum = 0.0f;
    #pragma unroll
    for (int d = 0; d < 32; d++) {
      float dd = __shfl(a[d], d);
      float yd = __shfl(acc, d) / dd;
      maha = fmaf(yd, yd, maha);
      ldsum += __logf(dd);
      acc = (rr > d) ? fmaf(-a[d], yd, acc) : acc;
    }
    if (lane == 0) pairv[pid] = -0.5 * ((double)maha + 2.0*(double)ldsum + DLOG2PI);
  }
  // ---- last-block fused final reduction ----
  __syncthreads();
  if (tid == 0) {
    __threadfence();
    unsigned old = atomicAdd(ticket, 1u);
    lastFlag = (old == NWB - 1) ? 1u : 0u;
  }
  __syncthreads();
  if (lastFlag) {
    __threadfence();
    __shared__ double rm[8], rs[8], rzm[8], rzs[8];
    double tm = -1e300, ts = 0.0;
    if (tid < NWB) { tm = partials[2*tid]; ts = partials[2*tid+1]; }
    double zm = -1e300, zs = 0.0;
    for (int p = tid; p < 1024; p += 512) {
      int i = p >> 5, j = p & 31;
      lse_merge(zm, zs, pairv[p], (double)wts[i] * (double)wts[j]);
    }
    #pragma unroll
    for (int off = 32; off > 0; off >>= 1) {
      double a2 = __shfl_down(tm, off), b2 = __shfl_down(ts, off);
      lse_merge(tm, ts, a2, b2);
      double c2 = __shfl_down(zm, off), d2 = __shfl_down(zs, off);
      lse_merge(zm, zs, c2, d2);
    }
    if ((tid & 63) == 0) { int w = tid >> 6; rm[w]=tm; rs[w]=ts; rzm[w]=zm; rzs[w]=zs; }
    __syncthreads();
    if (tid == 0) {
      for (int w = 1; w < 8; w++) { lse_merge(tm, ts, rm[w], rs[w]); lse_merge(zm, zs, rzm[w], rzs[w]); }
      double logT = tm + log(ts);
      double logz = zm + log(zs);
      out[0] = (float)((logz - logT) / (double)NPTS);
    }
  }
}

extern "C" void kernel_launch(void* const* d_in, const int* in_sizes, int n_in,
                              void* d_out, int out_size, void* d_ws, size_t ws_size,
                              hipStream_t stream) {
  const float* X     = (const float*)d_in[0];
  const float* means = (const float*)d_in[1];
  const float* chols = (const float*)d_in[2];
  const float* wts   = (const float*)d_in[3];
  float* out = (float*)d_out;
  char* ws = (char*)d_ws;
  float*    SigmaF   = (float*)ws;               // 131072 B
  uint4*    Afrag    = (uint4*)(ws + 131072);    // 98304  -> 229376
  float*    Kc       = (float*)(ws + 229376);    // 128    -> 229504
  float*    Sg       = (float*)(ws + 229504);    // 128    -> 229632
  double*   pairv    = (double*)(ws + 229632);   // 8192   -> 237824
  double*   partials = (double*)(ws + 237824);   // 4096   -> 241920
  unsigned* ticket   = (unsigned*)(ws + 241920); // 4      -> 241924

  setup_kernel<<<8, 256, 0, stream>>>(means, chols, wts, SigmaF, Afrag, Kc, Sg, ticket);
  work_kernel<<<NWB, 512, 0, stream>>>(X, means, wts, SigmaF, Afrag, Kc, Sg,
                                       pairv, partials, ticket, out);
}